// Round 1
// baseline (9529.689 us; speedup 1.0000x reference)
//
#include <hip/hip_runtime.h>

// ---------------------------------------------------------------------------
// GAT (2 layers) — round 0: correctness-first implementation.
// Layer = GEMM+logits kernel, then 2 edge passes (denom, aggregate) w/ atomics.
// segment_max omitted: logits bounded ~|10|, exp() safe in fp32, alpha invariant.
// ---------------------------------------------------------------------------

__device__ __forceinline__ float lrelu02(float x) {
    return x > 0.f ? x : 0.2f * x;
}

// h = x @ W  (row-major), plus per-head logit dots al_s/al_d via shfl reduce.
// Block = 64 threads; each group of OUTC=H*C lanes handles one node.
template<int IN_DIM, int H, int C>
__global__ void gemm_al_kernel(const float* __restrict__ x,
                               const float* __restrict__ W,
                               const float* __restrict__ a_src,
                               const float* __restrict__ a_dst,
                               float* __restrict__ h,
                               float* __restrict__ al_s,
                               float* __restrict__ al_d,
                               int n_nodes) {
    constexpr int OUTC = H * C;              // 64 (layer1) or 32 (layer2)
    constexpr int NPB  = 64 / OUTC;          // nodes per block
    int tid   = threadIdx.x;
    int local = tid / OUTC;
    int col   = tid - local * OUTC;
    int node  = blockIdx.x * NPB + local;
    if (node >= n_nodes) return;

    const float* xr = x + (size_t)node * IN_DIM;
    float acc = 0.f;
#pragma unroll
    for (int k = 0; k < IN_DIM; ++k)
        acc += xr[k] * W[k * OUTC + col];

    h[(size_t)node * OUTC + col] = acc;

    // reduce within each head's C lanes (C is a power of 2: 8 or 32)
    float vs = acc * a_src[col];
    float vd = acc * a_dst[col];
#pragma unroll
    for (int off = C / 2; off > 0; off >>= 1) {
        vs += __shfl_down(vs, off, C);
        vd += __shfl_down(vd, off, C);
    }
    if ((col & (C - 1)) == 0) {
        int head = col / C;
        al_s[(size_t)node * H + head] = vs;
        al_d[(size_t)node * H + head] = vd;
    }
}

// Pass 1 over edges: denom[dst,h] += exp(leaky_relu(al_s[src,h]+al_d[dst,h]))
template<int H>
__global__ void edge_denom_kernel(const int* __restrict__ ei,
                                  int e_real, int e_total,
                                  const float* __restrict__ al_s,
                                  const float* __restrict__ al_d,
                                  float* __restrict__ denom) {
    int i = blockIdx.x * blockDim.x + threadIdx.x;
    if (i >= e_total) return;
    int src, dst;
    if (i < e_real) { src = ei[i]; dst = ei[e_real + i]; }
    else            { src = dst = i - e_real; }          // self-loop
#pragma unroll
    for (int hh = 0; hh < H; ++hh) {
        float e = lrelu02(al_s[(size_t)src * H + hh] + al_d[(size_t)dst * H + hh]);
        atomicAdd(&denom[(size_t)dst * H + hh], __expf(e));
    }
}

// Pass 2 over edges: out[dst, h*C+c] += alpha * h[src, h*C+c]
template<int H, int C>
__global__ void edge_agg_kernel(const int* __restrict__ ei,
                                int e_real, int e_total,
                                const float* __restrict__ al_s,
                                const float* __restrict__ al_d,
                                const float* __restrict__ denom,
                                const float* __restrict__ h,
                                float* __restrict__ out) {
    int i = blockIdx.x * blockDim.x + threadIdx.x;
    if (i >= e_total) return;
    int src, dst;
    if (i < e_real) { src = ei[i]; dst = ei[e_real + i]; }
    else            { src = dst = i - e_real; }
#pragma unroll
    for (int hh = 0; hh < H; ++hh) {
        float e = lrelu02(al_s[(size_t)src * H + hh] + al_d[(size_t)dst * H + hh]);
        float alpha = __expf(e) / denom[(size_t)dst * H + hh];
        const float* hs = h   + (size_t)src * H * C + hh * C;
        float*       od = out + (size_t)dst * H * C + hh * C;
#pragma unroll
        for (int c = 0; c < C; ++c)
            atomicAdd(&od[c], hs[c] * alpha);
    }
}

// out[i] += b[i & mask]   (bias; cols is a power of 2)
__global__ void bias_add_kernel(float* __restrict__ out,
                                const float* __restrict__ b,
                                int mask, size_t total) {
    size_t i = (size_t)blockIdx.x * blockDim.x + threadIdx.x;
    if (i < total) out[i] += b[i & mask];
}

extern "C" void kernel_launch(void* const* d_in, const int* in_sizes, int n_in,
                              void* d_out, int out_size, void* d_ws, size_t ws_size,
                              hipStream_t stream) {
    const float* x   = (const float*)d_in[0];
    const int*   ei  = (const int*)  d_in[1];
    const float* W1  = (const float*)d_in[2];
    const float* as1 = (const float*)d_in[3];
    const float* ad1 = (const float*)d_in[4];
    const float* b1  = (const float*)d_in[5];
    const float* W2  = (const float*)d_in[6];
    const float* as2 = (const float*)d_in[7];
    const float* ad2 = (const float*)d_in[8];
    const float* b2  = (const float*)d_in[9];
    float* out = (float*)d_out;

    const int n       = in_sizes[0] / 128;   // 100000
    const int e_real  = in_sizes[1] / 2;     // 1600000
    const int e_total = e_real + n;          // + self-loops

    // workspace layout (floats); layer-2 buffers reuse layer-1's dead space
    float* ws   = (float*)d_ws;
    float* h1   = ws;                          // n*64   (layer2: h2, n*32)
    float* als1 = h1   + (size_t)n * 64;       // n*8    (layer2: als2, n)
    float* ald1 = als1 + (size_t)n * 8;        // n*8    (layer2: ald2, n)
    float* den1 = ald1 + (size_t)n * 8;        // n*8    (layer2: den2, n)
    float* agg1 = den1 + (size_t)n * 8;        // n*64   (layer-1 output, +b1)

    const int eb = (e_total + 255) / 256;

    // ---------------- layer 1: IN=128, H=8, C=8 ----------------
    hipMemsetAsync(den1, 0, (size_t)n * 8  * sizeof(float), stream);
    hipMemsetAsync(agg1, 0, (size_t)n * 64 * sizeof(float), stream);

    gemm_al_kernel<128, 8, 8><<<n, 64, 0, stream>>>(x, W1, as1, ad1,
                                                    h1, als1, ald1, n);
    edge_denom_kernel<8><<<eb, 256, 0, stream>>>(ei, e_real, e_total,
                                                 als1, ald1, den1);
    edge_agg_kernel<8, 8><<<eb, 256, 0, stream>>>(ei, e_real, e_total,
                                                  als1, ald1, den1, h1, agg1);
    bias_add_kernel<<<(int)(((size_t)n * 64 + 255) / 256), 256, 0, stream>>>(
        agg1, b1, 63, (size_t)n * 64);

    // ---------------- layer 2: IN=64, H=1, C=32 ----------------
    float* h2   = h1;    // n*32
    float* als2 = als1;  // n
    float* ald2 = ald1;  // n
    float* den2 = den1;  // n

    hipMemsetAsync(den2, 0, (size_t)n * sizeof(float), stream);
    hipMemsetAsync(out,  0, (size_t)out_size * sizeof(float), stream);

    gemm_al_kernel<64, 1, 32><<<(n + 1) / 2, 64, 0, stream>>>(agg1, W2, as2, ad2,
                                                              h2, als2, ald2, n);
    edge_denom_kernel<1><<<eb, 256, 0, stream>>>(ei, e_real, e_total,
                                                 als2, ald2, den2);
    edge_agg_kernel<1, 32><<<eb, 256, 0, stream>>>(ei, e_real, e_total,
                                                   als2, ald2, den2, h2, out);
    bias_add_kernel<<<(int)(((size_t)n * 32 + 255) / 256), 256, 0, stream>>>(
        out, b2, 31, (size_t)n * 32);
}

// Round 2
// 765.703 us; speedup vs baseline: 12.4457x; 12.4457x over previous
//
#include <hip/hip_runtime.h>

// ---------------------------------------------------------------------------
// GAT (2 layers) — round 2: CSR-by-dst gather, zero float atomics.
// Per launch: build CSR (deg histogram -> 2-level scan -> scatter), then per
// layer: GEMM+logits, then ONE gather pass per node computing
//   out = sum_j exp(e_j) h_src_j / sum_j exp(e_j)     (softmax fused, no max
// shift needed: logits are O(10), exp fits fp32 easily).
// ---------------------------------------------------------------------------

__device__ __forceinline__ float lrelu02(float x) {
    return x > 0.f ? x : 0.2f * x;
}

// ----------------------------- CSR build -----------------------------------

__global__ void deg_init_kernel(int* __restrict__ deg, int n) {
    int i = blockIdx.x * blockDim.x + threadIdx.x;
    if (i < n) deg[i] = 1;                    // self-loop contributes 1
}

__global__ void deg_hist_kernel(const int* __restrict__ ei, int e_real,
                                int* __restrict__ deg) {
    int i = blockIdx.x * blockDim.x + threadIdx.x;
    if (i < e_real) atomicAdd(&deg[ei[e_real + i]], 1);
}

// block-level inclusive scan (256 wide), write per-block totals
__global__ void scan1_kernel(const int* __restrict__ deg,
                             int* __restrict__ local_incl,
                             int* __restrict__ bsum, int n) {
    __shared__ int s[256];
    int tid = threadIdx.x;
    int i = blockIdx.x * 256 + tid;
    int v = (i < n) ? deg[i] : 0;
    s[tid] = v;
    __syncthreads();
    for (int off = 1; off < 256; off <<= 1) {
        int t = (tid >= off) ? s[tid - off] : 0;
        __syncthreads();
        s[tid] += t;
        __syncthreads();
    }
    if (i < n) local_incl[i] = s[tid];
    if (tid == 255) bsum[blockIdx.x] = s[255];
}

// single-block exclusive scan of block sums (nb <= 512)
__global__ void scan2_kernel(int* __restrict__ bsum, int nb) {
    __shared__ int s[512];
    int tid = threadIdx.x;
    int v = (tid < nb) ? bsum[tid] : 0;
    s[tid] = v;
    __syncthreads();
    for (int off = 1; off < 512; off <<= 1) {
        int t = (tid >= off) ? s[tid - off] : 0;
        __syncthreads();
        s[tid] += t;
        __syncthreads();
    }
    if (tid < nb) bsum[tid] = s[tid] - v;     // exclusive
}

// offsets[i] (exclusive), offsets[n] = total, cursor[i] = offsets[i]
__global__ void scan3_kernel(const int* __restrict__ deg,
                             const int* __restrict__ local_incl,
                             const int* __restrict__ bsum,
                             int* __restrict__ offsets,
                             int* __restrict__ cursor, int n) {
    int i = blockIdx.x * blockDim.x + threadIdx.x;
    if (i >= n) return;
    int excl = bsum[i >> 8] + local_incl[i] - deg[i];
    offsets[i] = excl;
    cursor[i]  = excl;
    if (i == n - 1) offsets[n] = bsum[i >> 8] + local_incl[i];
}

__global__ void scatter_kernel(const int* __restrict__ ei,
                               int e_real, int e_total,
                               int* __restrict__ cursor,
                               int* __restrict__ srcs) {
    int i = blockIdx.x * blockDim.x + threadIdx.x;
    if (i >= e_total) return;
    int src, dst;
    if (i < e_real) { src = ei[i]; dst = ei[e_real + i]; }
    else            { src = dst = i - e_real; }
    int pos = atomicAdd(&cursor[dst], 1);
    srcs[pos] = src;
}

// ------------------------- GEMM + attention logits --------------------------
// block = 256 threads; W staged in LDS; group of OUTC lanes per node.
template<int IN_DIM, int H, int C>
__global__ void gemm_al_kernel(const float* __restrict__ x,
                               const float* __restrict__ W,
                               const float* __restrict__ a_src,
                               const float* __restrict__ a_dst,
                               float* __restrict__ h,
                               float* __restrict__ al_s,
                               float* __restrict__ al_d,
                               int n_nodes) {
    constexpr int OUTC = H * C;              // 64 or 32
    constexpr int NPB  = 256 / OUTC;         // nodes per block
    __shared__ float Ws[IN_DIM * OUTC];
    int tid = threadIdx.x;
    for (int idx = tid; idx < IN_DIM * OUTC; idx += 256)
        Ws[idx] = W[idx];
    __syncthreads();

    int local = tid / OUTC;
    int col   = tid - local * OUTC;
    int node  = blockIdx.x * NPB + local;
    if (node >= n_nodes) return;

    const float* xr = x + (size_t)node * IN_DIM;
    float acc = 0.f;
#pragma unroll 8
    for (int k = 0; k < IN_DIM; ++k)
        acc += xr[k] * Ws[k * OUTC + col];

    h[(size_t)node * OUTC + col] = acc;

    float vs = acc * a_src[col];
    float vd = acc * a_dst[col];
#pragma unroll
    for (int off = C / 2; off > 0; off >>= 1) {
        vs += __shfl_down(vs, off, C);
        vd += __shfl_down(vd, off, C);
    }
    if ((col & (C - 1)) == 0) {
        int head = col / C;
        al_s[(size_t)node * H + head] = vs;
        al_d[(size_t)node * H + head] = vd;
    }
}

// ------------------------- fused gather aggregation -------------------------
// OUTC lanes per dst node; single pass: acc = sum exp(e)*h_src, dsum = sum exp.
template<int H, int C>
__global__ void gat_agg_kernel(const int* __restrict__ offsets,
                               const int* __restrict__ srcs,
                               const float* __restrict__ al_s,
                               const float* __restrict__ al_d,
                               const float* __restrict__ hfeat,
                               const float* __restrict__ bias,
                               float* __restrict__ out, int n) {
    constexpr int OUTC = H * C;
    int gt   = blockIdx.x * blockDim.x + threadIdx.x;
    int node = gt / OUTC;
    int lane = gt - node * OUTC;
    if (node >= n) return;
    int head = lane / C;

    int beg = offsets[node];
    int end = offsets[node + 1];
    float aldv = al_d[(size_t)node * H + head];

    float dsum = 0.f, acc = 0.f;
    for (int j = beg; j < end; ++j) {
        int s = srcs[j];
        float ex = __expf(lrelu02(al_s[(size_t)s * H + head] + aldv));
        dsum += ex;
        acc  += hfeat[(size_t)s * OUTC + lane] * ex;
    }
    out[(size_t)node * OUTC + lane] = acc / dsum + bias[lane];
}

// ---------------------------------------------------------------------------

extern "C" void kernel_launch(void* const* d_in, const int* in_sizes, int n_in,
                              void* d_out, int out_size, void* d_ws, size_t ws_size,
                              hipStream_t stream) {
    const float* x   = (const float*)d_in[0];
    const int*   ei  = (const int*)  d_in[1];
    const float* W1  = (const float*)d_in[2];
    const float* as1 = (const float*)d_in[3];
    const float* ad1 = (const float*)d_in[4];
    const float* b1  = (const float*)d_in[5];
    const float* W2  = (const float*)d_in[6];
    const float* as2 = (const float*)d_in[7];
    const float* ad2 = (const float*)d_in[8];
    const float* b2  = (const float*)d_in[9];
    float* out = (float*)d_out;

    const int n       = in_sizes[0] / 128;   // 100000
    const int e_real  = in_sizes[1] / 2;     // 1600000
    const int e_total = e_real + n;
    const int NB      = (n + 255) / 256;     // scan blocks (391)

    // ------------- workspace layout -------------
    float* ws   = (float*)d_ws;
    float* h1   = ws;                          // n*64 (layer2 reuses as h2: n*32)
    float* als1 = h1   + (size_t)n * 64;       // n*8  (layer2: n)
    float* ald1 = als1 + (size_t)n * 8;        // n*8  (layer2: n)
    float* agg1 = ald1 + (size_t)n * 8;        // n*64 (layer1 output)
    int* ip       = (int*)(agg1 + (size_t)n * 64);
    int* offsets  = ip;                        // n+1
    int* cursor   = offsets + (n + 1);         // n
    int* deg      = cursor + n;                // n
    int* lincl    = deg + n;                   // n
    int* bsum     = lincl + n;                 // 512
    int* srcs     = bsum + 512;                // e_total

    const int eb = (e_total + 255) / 256;
    const int nb256 = (n + 255) / 256;

    // ------------- CSR build (shared by both layers) -------------
    deg_init_kernel<<<nb256, 256, 0, stream>>>(deg, n);
    deg_hist_kernel<<<(e_real + 255) / 256, 256, 0, stream>>>(ei, e_real, deg);
    scan1_kernel<<<NB, 256, 0, stream>>>(deg, lincl, bsum, n);
    scan2_kernel<<<1, 512, 0, stream>>>(bsum, NB);
    scan3_kernel<<<nb256, 256, 0, stream>>>(deg, lincl, bsum, offsets, cursor, n);
    scatter_kernel<<<eb, 256, 0, stream>>>(ei, e_real, e_total, cursor, srcs);

    // ------------- layer 1: IN=128, H=8, C=8 -------------
    gemm_al_kernel<128, 8, 8><<<(n + 3) / 4, 256, 0, stream>>>(
        x, W1, as1, ad1, h1, als1, ald1, n);
    gat_agg_kernel<8, 8><<<(n * 64 + 255) / 256, 256, 0, stream>>>(
        offsets, srcs, als1, ald1, h1, b1, agg1, n);

    // ------------- layer 2: IN=64, H=1, C=32 -------------
    float* h2   = h1;
    float* als2 = als1;
    float* ald2 = ald1;
    gemm_al_kernel<64, 1, 32><<<(n + 7) / 8, 256, 0, stream>>>(
        agg1, W2, as2, ad2, h2, als2, ald2, n);
    gat_agg_kernel<1, 32><<<(n * 32 + 255) / 256, 256, 0, stream>>>(
        offsets, srcs, als2, ald2, h2, b2, out, n);
}

// Round 3
// 604.966 us; speedup vs baseline: 15.7524x; 1.2657x over previous
//
#include <hip/hip_runtime.h>
#include <hip/hip_bf16.h>

// ---------------------------------------------------------------------------
// GAT (2 layers) — round 3:
//   * register-tiled fp32 GEMM (8 nodes x 4 cols per thread, LDS-staged X/W)
//   * h stored as bf16 -> halves gather traffic in the aggregation pass
//   * CSR-by-dst gather aggregation (softmax fused, single pass, no atomics)
// ---------------------------------------------------------------------------

__device__ __forceinline__ float lrelu02(float x) { return x > 0.f ? x : 0.2f * x; }

__device__ __forceinline__ unsigned short f2bf(float v) {
    __hip_bfloat16 b = __float2bfloat16(v);
    return __builtin_bit_cast(unsigned short, b);
}
__device__ __forceinline__ float bf2f(unsigned short u) {
    return __bfloat162float(__builtin_bit_cast(__hip_bfloat16, u));
}

// ----------------------------- CSR build -----------------------------------

__global__ void deg_init_kernel(int* __restrict__ deg, int n) {
    int i = blockIdx.x * blockDim.x + threadIdx.x;
    if (i < n) deg[i] = 1;                    // self-loop contributes 1
}

__global__ void deg_hist_kernel(const int* __restrict__ ei, int e_real,
                                int* __restrict__ deg) {
    int i = blockIdx.x * blockDim.x + threadIdx.x;
    if (i < e_real) atomicAdd(&deg[ei[e_real + i]], 1);
}

__global__ void scan1_kernel(const int* __restrict__ deg,
                             int* __restrict__ local_incl,
                             int* __restrict__ bsum, int n) {
    __shared__ int s[256];
    int tid = threadIdx.x;
    int i = blockIdx.x * 256 + tid;
    int v = (i < n) ? deg[i] : 0;
    s[tid] = v;
    __syncthreads();
    for (int off = 1; off < 256; off <<= 1) {
        int t = (tid >= off) ? s[tid - off] : 0;
        __syncthreads();
        s[tid] += t;
        __syncthreads();
    }
    if (i < n) local_incl[i] = s[tid];
    if (tid == 255) bsum[blockIdx.x] = s[255];
}

__global__ void scan2_kernel(int* __restrict__ bsum, int nb) {
    __shared__ int s[512];
    int tid = threadIdx.x;
    int v = (tid < nb) ? bsum[tid] : 0;
    s[tid] = v;
    __syncthreads();
    for (int off = 1; off < 512; off <<= 1) {
        int t = (tid >= off) ? s[tid - off] : 0;
        __syncthreads();
        s[tid] += t;
        __syncthreads();
    }
    if (tid < nb) bsum[tid] = s[tid] - v;     // exclusive
}

__global__ void scan3_kernel(const int* __restrict__ deg,
                             const int* __restrict__ local_incl,
                             const int* __restrict__ bsum,
                             int* __restrict__ offsets,
                             int* __restrict__ cursor, int n) {
    int i = blockIdx.x * blockDim.x + threadIdx.x;
    if (i >= n) return;
    int excl = bsum[i >> 8] + local_incl[i] - deg[i];
    offsets[i] = excl;
    cursor[i]  = excl;
    if (i == n - 1) offsets[n] = bsum[i >> 8] + local_incl[i];
}

__global__ void scatter_kernel(const int* __restrict__ ei,
                               int e_real, int e_total,
                               int* __restrict__ cursor,
                               int* __restrict__ srcs) {
    int i = blockIdx.x * blockDim.x + threadIdx.x;
    if (i >= e_total) return;
    int src, dst;
    if (i < e_real) { src = ei[i]; dst = ei[e_real + i]; }
    else            { src = dst = i - e_real; }
    int pos = atomicAdd(&cursor[dst], 1);
    srcs[pos] = src;
}

// ------------------------- tiled GEMM + attention logits --------------------
// block = 256 threads; tile = NPT nodes x OUTC cols; thread = 8 nodes x 4 cols.
// X chunk staged in LDS padded (+1) rows; W chunk staged flat.
// h written as bf16; per-head logit dots reduced via shfl_xor.
template<int K, int OUTC, int H, int C, int NPT, int KCHUNK>
__global__ __launch_bounds__(256)
void gemm_al_kernel(const float* __restrict__ x,
                    const float* __restrict__ W,
                    const float* __restrict__ a_src,
                    const float* __restrict__ a_dst,
                    unsigned short* __restrict__ h,      // [n][OUTC] bf16
                    float* __restrict__ al_s,
                    float* __restrict__ al_d,
                    int n) {
    constexpr int COLG = OUTC / 4;           // col groups (16 or 8)
    constexpr int NG   = 256 / COLG;         // node groups
    static_assert(NG * 8 == NPT, "tile mismatch");
    constexpr int LDX  = KCHUNK + 1;
    __shared__ float Xs[NPT * LDX];
    __shared__ float Ws[KCHUNK * OUTC];

    const int t    = threadIdx.x;
    const int mg   = t / COLG;
    const int cg   = t % COLG;
    const int base = blockIdx.x * NPT;

    float acc[8][4];
#pragma unroll
    for (int i = 0; i < 8; ++i)
#pragma unroll
        for (int j = 0; j < 4; ++j) acc[i][j] = 0.f;

    for (int kc = 0; kc < K; kc += KCHUNK) {
        __syncthreads();
        // stage X chunk (transpose-free, padded rows)
        constexpr int F4R = KCHUNK / 4;          // float4 per row chunk
        constexpr int TOTF4 = NPT * F4R;         // 2048 for both layers
#pragma unroll
        for (int r = 0; r < TOTF4 / 256; ++r) {
            int f4   = r * 256 + t;
            int node = f4 / F4R;
            int kq   = f4 % F4R;
            int gn   = base + node; if (gn > n - 1) gn = n - 1;
            const float4 v = *(const float4*)&x[(size_t)gn * K + kc + kq * 4];
            float* d = &Xs[node * LDX + kq * 4];
            d[0] = v.x; d[1] = v.y; d[2] = v.z; d[3] = v.w;
        }
        // stage W chunk (rows are contiguous)
        constexpr int WF4 = KCHUNK * OUTC / 4;
        for (int idx = t; idx < WF4; idx += 256)
            *(float4*)&Ws[idx * 4] = *(const float4*)&W[(size_t)kc * OUTC + idx * 4];
        __syncthreads();

#pragma unroll 4
        for (int k = 0; k < KCHUNK; ++k) {
            float4 b = *(const float4*)&Ws[k * OUTC + cg * 4];
            float a[8];
#pragma unroll
            for (int i = 0; i < 8; ++i) a[i] = Xs[(mg * 8 + i) * LDX + k];
#pragma unroll
            for (int i = 0; i < 8; ++i) {
                acc[i][0] += a[i] * b.x;
                acc[i][1] += a[i] * b.y;
                acc[i][2] += a[i] * b.z;
                acc[i][3] += a[i] * b.w;
            }
        }
    }

    // epilogue: bf16 h write + per-head logit dots
    const float4 as4 = *(const float4*)&a_src[cg * 4];
    const float4 ad4 = *(const float4*)&a_dst[cg * 4];
    constexpr int GPH = C / 4;                // col-groups per head
    const int head = cg / GPH;
#pragma unroll
    for (int i = 0; i < 8; ++i) {
        int gn = base + mg * 8 + i;
        bool ok = gn < n;
        if (ok) {
            ushort4 hv;
            hv.x = f2bf(acc[i][0]); hv.y = f2bf(acc[i][1]);
            hv.z = f2bf(acc[i][2]); hv.w = f2bf(acc[i][3]);
            *(ushort4*)&h[(size_t)gn * OUTC + cg * 4] = hv;
        }
        float ps = acc[i][0] * as4.x + acc[i][1] * as4.y +
                   acc[i][2] * as4.z + acc[i][3] * as4.w;
        float pd = acc[i][0] * ad4.x + acc[i][1] * ad4.y +
                   acc[i][2] * ad4.z + acc[i][3] * ad4.w;
#pragma unroll
        for (int s = 1; s < GPH; s <<= 1) {
            ps += __shfl_xor(ps, s, 64);
            pd += __shfl_xor(pd, s, 64);
        }
        if (ok && (cg % GPH) == 0) {
            al_s[(size_t)gn * H + head] = ps;
            al_d[(size_t)gn * H + head] = pd;
        }
    }
}

// ------------------------- fused gather aggregation -------------------------
template<int H, int C>
__global__ void gat_agg_kernel(const int* __restrict__ offsets,
                               const int* __restrict__ srcs,
                               const float* __restrict__ al_s,
                               const float* __restrict__ al_d,
                               const unsigned short* __restrict__ hfeat, // bf16
                               const float* __restrict__ bias,
                               float* __restrict__ out, int n) {
    constexpr int OUTC = H * C;
    int gt   = blockIdx.x * blockDim.x + threadIdx.x;
    int node = gt / OUTC;
    int lane = gt - node * OUTC;
    if (node >= n) return;
    int head = lane / C;

    int beg = offsets[node];
    int end = offsets[node + 1];
    float aldv = al_d[(size_t)node * H + head];

    float dsum = 0.f, acc = 0.f;
    for (int j = beg; j < end; ++j) {
        int s = srcs[j];
        float ex = __expf(lrelu02(al_s[(size_t)s * H + head] + aldv));
        dsum += ex;
        acc  += bf2f(hfeat[(size_t)s * OUTC + lane]) * ex;
    }
    out[(size_t)node * OUTC + lane] = acc / dsum + bias[lane];
}

// ---------------------------------------------------------------------------

extern "C" void kernel_launch(void* const* d_in, const int* in_sizes, int n_in,
                              void* d_out, int out_size, void* d_ws, size_t ws_size,
                              hipStream_t stream) {
    const float* x   = (const float*)d_in[0];
    const int*   ei  = (const int*)  d_in[1];
    const float* W1  = (const float*)d_in[2];
    const float* as1 = (const float*)d_in[3];
    const float* ad1 = (const float*)d_in[4];
    const float* b1  = (const float*)d_in[5];
    const float* W2  = (const float*)d_in[6];
    const float* as2 = (const float*)d_in[7];
    const float* ad2 = (const float*)d_in[8];
    const float* b2  = (const float*)d_in[9];
    float* out = (float*)d_out;

    const int n       = in_sizes[0] / 128;   // 100000
    const int e_real  = in_sizes[1] / 2;     // 1600000
    const int e_total = e_real + n;
    const int NB      = (n + 255) / 256;     // scan blocks (391 <= 512)

    // ------------- workspace layout -------------
    unsigned short* h1u = (unsigned short*)d_ws;       // n*64 bf16 (l2: n*32)
    float* fws  = (float*)d_ws;
    float* als1 = fws  + (size_t)n * 32;               // n*8  (l2: n)
    float* ald1 = als1 + (size_t)n * 8;                // n*8  (l2: n)
    float* agg1 = ald1 + (size_t)n * 8;                // n*64 fp32 (layer1 out)
    int* offsets  = (int*)(agg1 + (size_t)n * 64);     // n+1
    int* cursor   = offsets + (n + 1);                 // n
    int* deg      = cursor + n;                        // n
    int* lincl    = deg + n;                           // n
    int* bsum     = lincl + n;                         // 512
    int* srcs     = bsum + 512;                        // e_total

    const int eb    = (e_total + 255) / 256;
    const int nb256 = (n + 255) / 256;

    // ------------- CSR build (shared by both layers) -------------
    deg_init_kernel<<<nb256, 256, 0, stream>>>(deg, n);
    deg_hist_kernel<<<(e_real + 255) / 256, 256, 0, stream>>>(ei, e_real, deg);
    scan1_kernel<<<NB, 256, 0, stream>>>(deg, lincl, bsum, n);
    scan2_kernel<<<1, 512, 0, stream>>>(bsum, NB);
    scan3_kernel<<<nb256, 256, 0, stream>>>(deg, lincl, bsum, offsets, cursor, n);
    scatter_kernel<<<eb, 256, 0, stream>>>(ei, e_real, e_total, cursor, srcs);

    // ------------- layer 1: K=128, H=8, C=8, tile 128x64 -------------
    gemm_al_kernel<128, 64, 8, 8, 128, 64><<<(n + 127) / 128, 256, 0, stream>>>(
        x, W1, as1, ad1, h1u, als1, ald1, n);
    gat_agg_kernel<8, 8><<<((size_t)n * 64 + 255) / 256, 256, 0, stream>>>(
        offsets, srcs, als1, ald1, h1u, b1, agg1, n);

    // ------------- layer 2: K=64, H=1, C=32, tile 256x32 -------------
    gemm_al_kernel<64, 32, 1, 32, 256, 32><<<(n + 255) / 256, 256, 0, stream>>>(
        agg1, W2, as2, ad2, h1u, als1, ald1, n);
    gat_agg_kernel<1, 32><<<((size_t)n * 32 + 255) / 256, 256, 0, stream>>>(
        offsets, srcs, als1, ald1, h1u, b2, out, n);
}

// Round 4
// 452.830 us; speedup vs baseline: 21.0447x; 1.3360x over previous
//
#include <hip/hip_runtime.h>
#include <hip/hip_bf16.h>

// ---------------------------------------------------------------------------
// GAT (2 layers) — round 4:
//   * agg kernel restructured: wave = 1 dst node; lane = (edge_slot, ch_group);
//     each lane gathers uint4 (8 bf16) -> 8/16 edges in flight per wave,
//     exp deduped to once per (edge,head); butterfly reduce over edge slots.
//   * register-tiled fp32 GEMM, h stored bf16, CSR build per launch.
// ---------------------------------------------------------------------------

__device__ __forceinline__ float lrelu02(float x) { return x > 0.f ? x : 0.2f * x; }

__device__ __forceinline__ unsigned short f2bf(float v) {
    __hip_bfloat16 b = __float2bfloat16(v);
    return __builtin_bit_cast(unsigned short, b);
}

// ----------------------------- CSR build -----------------------------------

__global__ void deg_init_kernel(int* __restrict__ deg, int n) {
    int i = blockIdx.x * blockDim.x + threadIdx.x;
    if (i < n) deg[i] = 1;                    // self-loop contributes 1
}

__global__ void deg_hist_kernel(const int* __restrict__ ei, int e_real,
                                int* __restrict__ deg) {
    int i = blockIdx.x * blockDim.x + threadIdx.x;
    if (i < e_real) atomicAdd(&deg[ei[e_real + i]], 1);
}

__global__ void scan1_kernel(const int* __restrict__ deg,
                             int* __restrict__ local_incl,
                             int* __restrict__ bsum, int n) {
    __shared__ int s[256];
    int tid = threadIdx.x;
    int i = blockIdx.x * 256 + tid;
    int v = (i < n) ? deg[i] : 0;
    s[tid] = v;
    __syncthreads();
    for (int off = 1; off < 256; off <<= 1) {
        int t = (tid >= off) ? s[tid - off] : 0;
        __syncthreads();
        s[tid] += t;
        __syncthreads();
    }
    if (i < n) local_incl[i] = s[tid];
    if (tid == 255) bsum[blockIdx.x] = s[255];
}

__global__ void scan2_kernel(int* __restrict__ bsum, int nb) {
    __shared__ int s[512];
    int tid = threadIdx.x;
    int v = (tid < nb) ? bsum[tid] : 0;
    s[tid] = v;
    __syncthreads();
    for (int off = 1; off < 512; off <<= 1) {
        int t = (tid >= off) ? s[tid - off] : 0;
        __syncthreads();
        s[tid] += t;
        __syncthreads();
    }
    if (tid < nb) bsum[tid] = s[tid] - v;     // exclusive
}

__global__ void scan3_kernel(const int* __restrict__ deg,
                             const int* __restrict__ local_incl,
                             const int* __restrict__ bsum,
                             int* __restrict__ offsets,
                             int* __restrict__ cursor, int n) {
    int i = blockIdx.x * blockDim.x + threadIdx.x;
    if (i >= n) return;
    int excl = bsum[i >> 8] + local_incl[i] - deg[i];
    offsets[i] = excl;
    cursor[i]  = excl;
    if (i == n - 1) offsets[n] = bsum[i >> 8] + local_incl[i];
}

__global__ void scatter_kernel(const int* __restrict__ ei,
                               int e_real, int e_total,
                               int* __restrict__ cursor,
                               int* __restrict__ srcs) {
    int i = blockIdx.x * blockDim.x + threadIdx.x;
    if (i >= e_total) return;
    int src, dst;
    if (i < e_real) { src = ei[i]; dst = ei[e_real + i]; }
    else            { src = dst = i - e_real; }
    int pos = atomicAdd(&cursor[dst], 1);
    srcs[pos] = src;
}

// ------------------------- tiled GEMM + attention logits --------------------
template<int K, int OUTC, int H, int C, int NPT, int KCHUNK>
__global__ __launch_bounds__(256)
void gemm_al_kernel(const float* __restrict__ x,
                    const float* __restrict__ W,
                    const float* __restrict__ a_src,
                    const float* __restrict__ a_dst,
                    unsigned short* __restrict__ h,      // [n][OUTC] bf16
                    float* __restrict__ al_s,
                    float* __restrict__ al_d,
                    int n) {
    constexpr int COLG = OUTC / 4;
    constexpr int NG   = 256 / COLG;
    static_assert(NG * 8 == NPT, "tile mismatch");
    constexpr int LDX  = KCHUNK + 1;
    __shared__ float Xs[NPT * LDX];
    __shared__ float Ws[KCHUNK * OUTC];

    const int t    = threadIdx.x;
    const int mg   = t / COLG;
    const int cg   = t % COLG;
    const int base = blockIdx.x * NPT;

    float acc[8][4];
#pragma unroll
    for (int i = 0; i < 8; ++i)
#pragma unroll
        for (int j = 0; j < 4; ++j) acc[i][j] = 0.f;

    for (int kc = 0; kc < K; kc += KCHUNK) {
        __syncthreads();
        constexpr int F4R = KCHUNK / 4;
        constexpr int TOTF4 = NPT * F4R;
#pragma unroll
        for (int r = 0; r < TOTF4 / 256; ++r) {
            int f4   = r * 256 + t;
            int node = f4 / F4R;
            int kq   = f4 % F4R;
            int gn   = base + node; if (gn > n - 1) gn = n - 1;
            const float4 v = *(const float4*)&x[(size_t)gn * K + kc + kq * 4];
            float* d = &Xs[node * LDX + kq * 4];
            d[0] = v.x; d[1] = v.y; d[2] = v.z; d[3] = v.w;
        }
        constexpr int WF4 = KCHUNK * OUTC / 4;
        for (int idx = t; idx < WF4; idx += 256)
            *(float4*)&Ws[idx * 4] = *(const float4*)&W[(size_t)kc * OUTC + idx * 4];
        __syncthreads();

#pragma unroll 4
        for (int k = 0; k < KCHUNK; ++k) {
            float4 b = *(const float4*)&Ws[k * OUTC + cg * 4];
            float a[8];
#pragma unroll
            for (int i = 0; i < 8; ++i) a[i] = Xs[(mg * 8 + i) * LDX + k];
#pragma unroll
            for (int i = 0; i < 8; ++i) {
                acc[i][0] += a[i] * b.x;
                acc[i][1] += a[i] * b.y;
                acc[i][2] += a[i] * b.z;
                acc[i][3] += a[i] * b.w;
            }
        }
    }

    const float4 as4 = *(const float4*)&a_src[cg * 4];
    const float4 ad4 = *(const float4*)&a_dst[cg * 4];
    constexpr int GPH = C / 4;
    const int head = cg / GPH;
#pragma unroll
    for (int i = 0; i < 8; ++i) {
        int gn = base + mg * 8 + i;
        bool ok = gn < n;
        if (ok) {
            ushort4 hv;
            hv.x = f2bf(acc[i][0]); hv.y = f2bf(acc[i][1]);
            hv.z = f2bf(acc[i][2]); hv.w = f2bf(acc[i][3]);
            *(ushort4*)&h[(size_t)gn * OUTC + cg * 4] = hv;
        }
        float ps = acc[i][0] * as4.x + acc[i][1] * as4.y +
                   acc[i][2] * as4.z + acc[i][3] * as4.w;
        float pd = acc[i][0] * ad4.x + acc[i][1] * ad4.y +
                   acc[i][2] * ad4.z + acc[i][3] * ad4.w;
#pragma unroll
        for (int s = 1; s < GPH; s <<= 1) {
            ps += __shfl_xor(ps, s, 64);
            pd += __shfl_xor(pd, s, 64);
        }
        if (ok && (cg % GPH) == 0) {
            al_s[(size_t)gn * H + head] = ps;
            al_d[(size_t)gn * H + head] = pd;
        }
    }
}

// ------------------------- fused gather aggregation -------------------------
// wave = 1 dst node. lane = es*CG + cg: ES edge slots x CG channel-groups of
// 8 channels (uint4 = 8 bf16 = 16B per lane). Butterfly-reduce over edge
// slots at the end; lanes es==0 write OUTC floats.
template<int H, int C>
__global__ __launch_bounds__(256)
void gat_agg_kernel(const int* __restrict__ offsets,
                    const int* __restrict__ srcs,
                    const float* __restrict__ al_s,
                    const float* __restrict__ al_d,
                    const unsigned short* __restrict__ hfeat, // bf16
                    const float* __restrict__ bias,
                    float* __restrict__ out, int n) {
    constexpr int OUTC = H * C;
    constexpr int CG   = OUTC / 8;           // channel groups (8 or 4)
    constexpr int ES   = 64 / CG;            // edge slots (8 or 16)
    const int wid  = (int)((blockIdx.x * blockDim.x + threadIdx.x) >> 6);
    const int lane = threadIdx.x & 63;
    const int cg   = lane % CG;
    const int es   = lane / CG;
    if (wid >= n) return;
    const int head = (cg * 8) / C;

    const float aldv = al_d[(size_t)wid * H + head];
    const int beg = offsets[wid];
    const int end = offsets[wid + 1];

    float acc[8];
#pragma unroll
    for (int q = 0; q < 8; ++q) acc[q] = 0.f;
    float dsum = 0.f;

    for (int j0 = beg; j0 < end; j0 += ES) {
        int j = j0 + es;
        bool v = j < end;
        int s = srcs[v ? j : beg];           // clamp -> dup address, cache hit
        float ex = v ? __expf(lrelu02(al_s[(size_t)s * H + head] + aldv)) : 0.f;
        const uint4 hv = *(const uint4*)&hfeat[(size_t)s * OUTC + cg * 8];
        unsigned du[4] = {hv.x, hv.y, hv.z, hv.w};
#pragma unroll
        for (int q = 0; q < 4; ++q) {
            float flo = __uint_as_float(du[q] << 16);
            float fhi = __uint_as_float(du[q] & 0xffff0000u);
            acc[2 * q]     += flo * ex;
            acc[2 * q + 1] += fhi * ex;
        }
        dsum += ex;
    }

    // reduce across edge slots (lanes with same cg)
#pragma unroll
    for (int sh = CG; sh < 64; sh <<= 1) {
        dsum += __shfl_xor(dsum, sh, 64);
#pragma unroll
        for (int q = 0; q < 8; ++q) acc[q] += __shfl_xor(acc[q], sh, 64);
    }

    if (es == 0) {
        float inv = 1.f / dsum;
        float4 o0, o1;
        o0.x = acc[0] * inv + bias[cg * 8 + 0];
        o0.y = acc[1] * inv + bias[cg * 8 + 1];
        o0.z = acc[2] * inv + bias[cg * 8 + 2];
        o0.w = acc[3] * inv + bias[cg * 8 + 3];
        o1.x = acc[4] * inv + bias[cg * 8 + 4];
        o1.y = acc[5] * inv + bias[cg * 8 + 5];
        o1.z = acc[6] * inv + bias[cg * 8 + 6];
        o1.w = acc[7] * inv + bias[cg * 8 + 7];
        *(float4*)&out[(size_t)wid * OUTC + cg * 8]     = o0;
        *(float4*)&out[(size_t)wid * OUTC + cg * 8 + 4] = o1;
    }
}

// ---------------------------------------------------------------------------

extern "C" void kernel_launch(void* const* d_in, const int* in_sizes, int n_in,
                              void* d_out, int out_size, void* d_ws, size_t ws_size,
                              hipStream_t stream) {
    const float* x   = (const float*)d_in[0];
    const int*   ei  = (const int*)  d_in[1];
    const float* W1  = (const float*)d_in[2];
    const float* as1 = (const float*)d_in[3];
    const float* ad1 = (const float*)d_in[4];
    const float* b1  = (const float*)d_in[5];
    const float* W2  = (const float*)d_in[6];
    const float* as2 = (const float*)d_in[7];
    const float* ad2 = (const float*)d_in[8];
    const float* b2  = (const float*)d_in[9];
    float* out = (float*)d_out;

    const int n       = in_sizes[0] / 128;   // 100000
    const int e_real  = in_sizes[1] / 2;     // 1600000
    const int e_total = e_real + n;
    const int NB      = (n + 255) / 256;     // scan blocks (391 <= 512)

    // ------------- workspace layout -------------
    unsigned short* h1u = (unsigned short*)d_ws;       // n*64 bf16 (l2: n*32)
    float* fws  = (float*)d_ws;
    float* als1 = fws  + (size_t)n * 32;               // n*8  (l2: n)
    float* ald1 = als1 + (size_t)n * 8;                // n*8  (l2: n)
    float* agg1 = ald1 + (size_t)n * 8;                // n*64 fp32 (layer1 out)
    int* offsets  = (int*)(agg1 + (size_t)n * 64);     // n+1
    int* cursor   = offsets + (n + 1);                 // n
    int* deg      = cursor + n;                        // n
    int* lincl    = deg + n;                           // n
    int* bsum     = lincl + n;                         // 512
    int* srcs     = bsum + 512;                        // e_total

    const int eb    = (e_total + 255) / 256;
    const int nb256 = (n + 255) / 256;

    // ------------- CSR build (shared by both layers) -------------
    deg_init_kernel<<<nb256, 256, 0, stream>>>(deg, n);
    deg_hist_kernel<<<(e_real + 255) / 256, 256, 0, stream>>>(ei, e_real, deg);
    scan1_kernel<<<NB, 256, 0, stream>>>(deg, lincl, bsum, n);
    scan2_kernel<<<1, 512, 0, stream>>>(bsum, NB);
    scan3_kernel<<<nb256, 256, 0, stream>>>(deg, lincl, bsum, offsets, cursor, n);
    scatter_kernel<<<eb, 256, 0, stream>>>(ei, e_real, e_total, cursor, srcs);

    // ------------- layer 1: K=128, H=8, C=8 -------------
    gemm_al_kernel<128, 64, 8, 8, 128, 64><<<(n + 127) / 128, 256, 0, stream>>>(
        x, W1, as1, ad1, h1u, als1, ald1, n);
    gat_agg_kernel<8, 8><<<(n + 3) / 4, 256, 0, stream>>>(
        offsets, srcs, als1, ald1, h1u, b1, agg1, n);

    // ------------- layer 2: K=64, H=1, C=32 -------------
    gemm_al_kernel<64, 32, 1, 32, 256, 32><<<(n + 255) / 256, 256, 0, stream>>>(
        agg1, W2, as2, ad2, h1u, als1, ald1, n);
    gat_agg_kernel<1, 32><<<(n + 3) / 4, 256, 0, stream>>>(
        offsets, srcs, als1, ald1, h1u, b2, out, n);
}

// Round 5
// 398.024 us; speedup vs baseline: 23.9425x; 1.1377x over previous
//
#include <hip/hip_runtime.h>
#include <hip/hip_bf16.h>

// ---------------------------------------------------------------------------
// GAT (2 layers) — round 5:
//   * CSR scatter + degree histogram partitioned by dst-range with
//     partition = blockIdx & 7  ->  XCD-exclusive write windows (round-robin
//     blockIdx->XCD mapping). Kills the ~16x write amplification of the
//     random 4B scatter (108 MB -> ~srcs size).
//   * everything else: R4 structure (tiled GEMM, bf16 h, edge-slot gather agg)
// ---------------------------------------------------------------------------

__device__ __forceinline__ float lrelu02(float x) { return x > 0.f ? x : 0.2f * x; }

__device__ __forceinline__ unsigned short f2bf(float v) {
    __hip_bfloat16 b = __float2bfloat16(v);
    return __builtin_bit_cast(unsigned short, b);
}

// ----------------------------- CSR build -----------------------------------

__global__ void deg_init_kernel(int* __restrict__ deg, int n) {
    int i = blockIdx.x * blockDim.x + threadIdx.x;
    if (i < n) deg[i] = 1;                    // self-loop contributes 1
}

// partition = blockIdx&7 (XCD-exclusive dst window); slice = blockIdx>>3
__global__ void deg_hist_kernel(const int* __restrict__ ei, int e_real,
                                unsigned M, int* __restrict__ deg) {
    const int part   = blockIdx.x & 7;
    const int slice  = blockIdx.x >> 3;
    const int nsl    = gridDim.x >> 3;
    const int stride = nsl * blockDim.x;
    for (int i = slice * blockDim.x + threadIdx.x; i < e_real; i += stride) {
        int dst = ei[e_real + i];
        if ((int)__umulhi((unsigned)dst, M) == part)
            atomicAdd(&deg[dst], 1);
    }
}

__global__ void scan1_kernel(const int* __restrict__ deg,
                             int* __restrict__ local_incl,
                             int* __restrict__ bsum, int n) {
    __shared__ int s[256];
    int tid = threadIdx.x;
    int i = blockIdx.x * 256 + tid;
    int v = (i < n) ? deg[i] : 0;
    s[tid] = v;
    __syncthreads();
    for (int off = 1; off < 256; off <<= 1) {
        int t = (tid >= off) ? s[tid - off] : 0;
        __syncthreads();
        s[tid] += t;
        __syncthreads();
    }
    if (i < n) local_incl[i] = s[tid];
    if (tid == 255) bsum[blockIdx.x] = s[255];
}

__global__ void scan2_kernel(int* __restrict__ bsum, int nb) {
    __shared__ int s[512];
    int tid = threadIdx.x;
    int v = (tid < nb) ? bsum[tid] : 0;
    s[tid] = v;
    __syncthreads();
    for (int off = 1; off < 512; off <<= 1) {
        int t = (tid >= off) ? s[tid - off] : 0;
        __syncthreads();
        s[tid] += t;
        __syncthreads();
    }
    if (tid < nb) bsum[tid] = s[tid] - v;     // exclusive
}

__global__ void scan3_kernel(const int* __restrict__ deg,
                             const int* __restrict__ local_incl,
                             const int* __restrict__ bsum,
                             int* __restrict__ offsets,
                             int* __restrict__ cursor, int n) {
    int i = blockIdx.x * blockDim.x + threadIdx.x;
    if (i >= n) return;
    int excl = bsum[i >> 8] + local_incl[i] - deg[i];
    offsets[i] = excl;
    cursor[i]  = excl;
    if (i == n - 1) offsets[n] = bsum[i >> 8] + local_incl[i];
}

// partitioned like deg_hist: each XCD owns a contiguous srcs/cursor window
__global__ void scatter_kernel(const int* __restrict__ ei,
                               int e_real, int e_total, unsigned M,
                               int* __restrict__ cursor,
                               int* __restrict__ srcs) {
    const int part   = blockIdx.x & 7;
    const int slice  = blockIdx.x >> 3;
    const int nsl    = gridDim.x >> 3;
    const int stride = nsl * blockDim.x;
    for (int i = slice * blockDim.x + threadIdx.x; i < e_total; i += stride) {
        int src, dst;
        if (i < e_real) { src = ei[i]; dst = ei[e_real + i]; }
        else            { src = dst = i - e_real; }
        if ((int)__umulhi((unsigned)dst, M) == part) {
            int pos = atomicAdd(&cursor[dst], 1);
            srcs[pos] = src;
        }
    }
}

// ------------------------- tiled GEMM + attention logits --------------------
template<int K, int OUTC, int H, int C, int NPT, int KCHUNK>
__global__ __launch_bounds__(256)
void gemm_al_kernel(const float* __restrict__ x,
                    const float* __restrict__ W,
                    const float* __restrict__ a_src,
                    const float* __restrict__ a_dst,
                    unsigned short* __restrict__ h,      // [n][OUTC] bf16
                    float* __restrict__ al_s,
                    float* __restrict__ al_d,
                    int n) {
    constexpr int COLG = OUTC / 4;
    constexpr int NG   = 256 / COLG;
    static_assert(NG * 8 == NPT, "tile mismatch");
    constexpr int LDX  = KCHUNK + 1;
    __shared__ float Xs[NPT * LDX];
    __shared__ float Ws[KCHUNK * OUTC];

    const int t    = threadIdx.x;
    const int mg   = t / COLG;
    const int cg   = t % COLG;
    const int base = blockIdx.x * NPT;

    float acc[8][4];
#pragma unroll
    for (int i = 0; i < 8; ++i)
#pragma unroll
        for (int j = 0; j < 4; ++j) acc[i][j] = 0.f;

    for (int kc = 0; kc < K; kc += KCHUNK) {
        __syncthreads();
        constexpr int F4R = KCHUNK / 4;
        constexpr int TOTF4 = NPT * F4R;
#pragma unroll
        for (int r = 0; r < TOTF4 / 256; ++r) {
            int f4   = r * 256 + t;
            int node = f4 / F4R;
            int kq   = f4 % F4R;
            int gn   = base + node; if (gn > n - 1) gn = n - 1;
            const float4 v = *(const float4*)&x[(size_t)gn * K + kc + kq * 4];
            float* d = &Xs[node * LDX + kq * 4];
            d[0] = v.x; d[1] = v.y; d[2] = v.z; d[3] = v.w;
        }
        constexpr int WF4 = KCHUNK * OUTC / 4;
        for (int idx = t; idx < WF4; idx += 256)
            *(float4*)&Ws[idx * 4] = *(const float4*)&W[(size_t)kc * OUTC + idx * 4];
        __syncthreads();

#pragma unroll 4
        for (int k = 0; k < KCHUNK; ++k) {
            float4 b = *(const float4*)&Ws[k * OUTC + cg * 4];
            float a[8];
#pragma unroll
            for (int i = 0; i < 8; ++i) a[i] = Xs[(mg * 8 + i) * LDX + k];
#pragma unroll
            for (int i = 0; i < 8; ++i) {
                acc[i][0] += a[i] * b.x;
                acc[i][1] += a[i] * b.y;
                acc[i][2] += a[i] * b.z;
                acc[i][3] += a[i] * b.w;
            }
        }
    }

    const float4 as4 = *(const float4*)&a_src[cg * 4];
    const float4 ad4 = *(const float4*)&a_dst[cg * 4];
    constexpr int GPH = C / 4;
    const int head = cg / GPH;
#pragma unroll
    for (int i = 0; i < 8; ++i) {
        int gn = base + mg * 8 + i;
        bool ok = gn < n;
        if (ok) {
            ushort4 hv;
            hv.x = f2bf(acc[i][0]); hv.y = f2bf(acc[i][1]);
            hv.z = f2bf(acc[i][2]); hv.w = f2bf(acc[i][3]);
            *(ushort4*)&h[(size_t)gn * OUTC + cg * 4] = hv;
        }
        float ps = acc[i][0] * as4.x + acc[i][1] * as4.y +
                   acc[i][2] * as4.z + acc[i][3] * as4.w;
        float pd = acc[i][0] * ad4.x + acc[i][1] * ad4.y +
                   acc[i][2] * ad4.z + acc[i][3] * ad4.w;
#pragma unroll
        for (int s = 1; s < GPH; s <<= 1) {
            ps += __shfl_xor(ps, s, 64);
            pd += __shfl_xor(pd, s, 64);
        }
        if (ok && (cg % GPH) == 0) {
            al_s[(size_t)gn * H + head] = ps;
            al_d[(size_t)gn * H + head] = pd;
        }
    }
}

// ------------------------- fused gather aggregation -------------------------
// wave = 1 dst node; lane = (edge_slot es, channel_group cg of 8 bf16).
template<int H, int C>
__global__ __launch_bounds__(256)
void gat_agg_kernel(const int* __restrict__ offsets,
                    const int* __restrict__ srcs,
                    const float* __restrict__ al_s,
                    const float* __restrict__ al_d,
                    const unsigned short* __restrict__ hfeat, // bf16
                    const float* __restrict__ bias,
                    float* __restrict__ out, int n) {
    constexpr int OUTC = H * C;
    constexpr int CG   = OUTC / 8;           // channel groups (8 or 4)
    constexpr int ES   = 64 / CG;            // edge slots (8 or 16)
    const int wid  = (int)((blockIdx.x * blockDim.x + threadIdx.x) >> 6);
    const int lane = threadIdx.x & 63;
    const int cg   = lane % CG;
    const int es   = lane / CG;
    if (wid >= n) return;
    const int head = (cg * 8) / C;

    const float aldv = al_d[(size_t)wid * H + head];
    const int beg = offsets[wid];
    const int end = offsets[wid + 1];

    float acc[8];
#pragma unroll
    for (int q = 0; q < 8; ++q) acc[q] = 0.f;
    float dsum = 0.f;

    for (int j0 = beg; j0 < end; j0 += ES) {
        int j = j0 + es;
        bool v = j < end;
        int s = srcs[v ? j : beg];           // clamp -> dup address, cache hit
        float ex = v ? __expf(lrelu02(al_s[(size_t)s * H + head] + aldv)) : 0.f;
        const uint4 hv = *(const uint4*)&hfeat[(size_t)s * OUTC + cg * 8];
        unsigned du[4] = {hv.x, hv.y, hv.z, hv.w};
#pragma unroll
        for (int q = 0; q < 4; ++q) {
            float flo = __uint_as_float(du[q] << 16);
            float fhi = __uint_as_float(du[q] & 0xffff0000u);
            acc[2 * q]     += flo * ex;
            acc[2 * q + 1] += fhi * ex;
        }
        dsum += ex;
    }

#pragma unroll
    for (int sh = CG; sh < 64; sh <<= 1) {
        dsum += __shfl_xor(dsum, sh, 64);
#pragma unroll
        for (int q = 0; q < 8; ++q) acc[q] += __shfl_xor(acc[q], sh, 64);
    }

    if (es == 0) {
        float inv = 1.f / dsum;
        float4 o0, o1;
        o0.x = acc[0] * inv + bias[cg * 8 + 0];
        o0.y = acc[1] * inv + bias[cg * 8 + 1];
        o0.z = acc[2] * inv + bias[cg * 8 + 2];
        o0.w = acc[3] * inv + bias[cg * 8 + 3];
        o1.x = acc[4] * inv + bias[cg * 8 + 4];
        o1.y = acc[5] * inv + bias[cg * 8 + 5];
        o1.z = acc[6] * inv + bias[cg * 8 + 6];
        o1.w = acc[7] * inv + bias[cg * 8 + 7];
        *(float4*)&out[(size_t)wid * OUTC + cg * 8]     = o0;
        *(float4*)&out[(size_t)wid * OUTC + cg * 8 + 4] = o1;
    }
}

// ---------------------------------------------------------------------------

extern "C" void kernel_launch(void* const* d_in, const int* in_sizes, int n_in,
                              void* d_out, int out_size, void* d_ws, size_t ws_size,
                              hipStream_t stream) {
    const float* x   = (const float*)d_in[0];
    const int*   ei  = (const int*)  d_in[1];
    const float* W1  = (const float*)d_in[2];
    const float* as1 = (const float*)d_in[3];
    const float* ad1 = (const float*)d_in[4];
    const float* b1  = (const float*)d_in[5];
    const float* W2  = (const float*)d_in[6];
    const float* as2 = (const float*)d_in[7];
    const float* ad2 = (const float*)d_in[8];
    const float* b2  = (const float*)d_in[9];
    float* out = (float*)d_out;

    const int n       = in_sizes[0] / 128;   // 100000
    const int e_real  = in_sizes[1] / 2;     // 1600000
    const int e_total = e_real + n;
    const int NB      = (n + 255) / 256;     // scan blocks (391 <= 512)
    // monotone dst -> partition in [0,8): part = umulhi(dst, M8)
    const unsigned M8 = (unsigned)((8ull << 32) / (unsigned)n);

    // ------------- workspace layout -------------
    unsigned short* h1u = (unsigned short*)d_ws;       // n*64 bf16 (l2: n*32)
    float* fws  = (float*)d_ws;
    float* als1 = fws  + (size_t)n * 32;               // n*8  (l2: n)
    float* ald1 = als1 + (size_t)n * 8;                // n*8  (l2: n)
    float* agg1 = ald1 + (size_t)n * 8;                // n*64 fp32 (layer1 out)
    int* offsets  = (int*)(agg1 + (size_t)n * 64);     // n+1
    int* cursor   = offsets + (n + 1);                 // n
    int* deg      = cursor + n;                        // n
    int* lincl    = deg + n;                           // n
    int* bsum     = lincl + n;                         // 512
    int* srcs     = bsum + 512;                        // e_total

    const int nb256 = (n + 255) / 256;
    const int PART_BLOCKS = 8 * 120;                   // 120 slices per partition

    // ------------- CSR build (shared by both layers) -------------
    deg_init_kernel<<<nb256, 256, 0, stream>>>(deg, n);
    deg_hist_kernel<<<PART_BLOCKS, 256, 0, stream>>>(ei, e_real, M8, deg);
    scan1_kernel<<<NB, 256, 0, stream>>>(deg, lincl, bsum, n);
    scan2_kernel<<<1, 512, 0, stream>>>(bsum, NB);
    scan3_kernel<<<nb256, 256, 0, stream>>>(deg, lincl, bsum, offsets, cursor, n);
    scatter_kernel<<<PART_BLOCKS, 256, 0, stream>>>(ei, e_real, e_total, M8,
                                                    cursor, srcs);

    // ------------- layer 1: K=128, H=8, C=8 -------------
    gemm_al_kernel<128, 64, 8, 8, 128, 64><<<(n + 127) / 128, 256, 0, stream>>>(
        x, W1, as1, ad1, h1u, als1, ald1, n);
    gat_agg_kernel<8, 8><<<(n + 3) / 4, 256, 0, stream>>>(
        offsets, srcs, als1, ald1, h1u, b1, agg1, n);

    // ------------- layer 2: K=64, H=1, C=32 -------------
    gemm_al_kernel<64, 32, 1, 32, 256, 32><<<(n + 255) / 256, 256, 0, stream>>>(
        agg1, W2, as2, ad2, h1u, als1, ald1, n);
    gat_agg_kernel<1, 32><<<(n + 3) / 4, 256, 0, stream>>>(
        offsets, srcs, als1, ald1, h1u, b2, out, n);
}